// Round 1
// baseline (1031.872 us; speedup 1.0000x reference)
//
#include <hip/hip_runtime.h>
#include <hip/hip_fp16.h>
#include <math.h>

#define BB 8
#define NN 1024
#define DD 64
#define EPSF 0.05f
#define INV_EPS 20.0f
#define MAX_ITER 100
// threshold on SUM of |du| over B*N (reference: mean < 1e-6)
#define ERR_SUM_THRESH 8.192e-3f

typedef _Float16 half8 __attribute__((ext_vector_type(8)));

__device__ __forceinline__ float wave_max64(float x) {
#pragma unroll
    for (int off = 1; off < 64; off <<= 1) x = fmaxf(x, __shfl_xor(x, off));
    return x;
}
__device__ __forceinline__ float wave_sum64(float x) {
#pragma unroll
    for (int off = 1; off < 64; off <<= 1) x += __shfl_xor(x, off);
    return x;
}

// ---------------- normalize rows of (nrows, 64) ----------------
__global__ __launch_bounds__(256) void norm_kernel(const float* __restrict__ in,
                                                   float* __restrict__ out, int nrows) {
    int wave = (blockIdx.x * blockDim.x + threadIdx.x) >> 6;
    int lane = threadIdx.x & 63;
    if (wave >= nrows) return;
    float x = in[(size_t)wave * DD + lane];
    float ss = wave_sum64(x * x);
    float n = fmaxf(sqrtf(ss), 1e-12f);
    out[(size_t)wave * DD + lane] = x / n;
}

// ---------------- C = 1 - Qn Kn^T, store fp16 C and C^T ----------------
__global__ __launch_bounds__(256) void cost_kernel(const float* __restrict__ Q,
                                                   const float* __restrict__ K,
                                                   _Float16* __restrict__ C,
                                                   _Float16* __restrict__ CT) {
    __shared__ float Qs[64][65];
    __shared__ float Ks[64][65];
    int b = blockIdx.z;
    int i0 = blockIdx.y * 64, j0 = blockIdx.x * 64;
    const float* Qb = Q + ((size_t)b * NN + i0) * DD;
    const float* Kb = K + ((size_t)b * NN + j0) * DD;
    int tx = threadIdx.x, ty = threadIdx.y;
    int tid = ty * 16 + tx;
#pragma unroll
    for (int kk = 0; kk < 4; ++kk) {
        int c = tid + 256 * kk;     // float4 chunk id, 0..1023
        int row = c >> 4;
        int c4 = c & 15;
        float4 qv = ((const float4*)(Qb + row * DD))[c4];
        Qs[row][c4 * 4 + 0] = qv.x; Qs[row][c4 * 4 + 1] = qv.y;
        Qs[row][c4 * 4 + 2] = qv.z; Qs[row][c4 * 4 + 3] = qv.w;
        float4 kv = ((const float4*)(Kb + row * DD))[c4];
        Ks[row][c4 * 4 + 0] = kv.x; Ks[row][c4 * 4 + 1] = kv.y;
        Ks[row][c4 * 4 + 2] = kv.z; Ks[row][c4 * 4 + 3] = kv.w;
    }
    __syncthreads();
    float acc[4][4] = {};
#pragma unroll 16
    for (int d = 0; d < 64; ++d) {
        float qv[4], kv[4];
#pragma unroll
        for (int rr = 0; rr < 4; ++rr) qv[rr] = Qs[ty * 4 + rr][d];
#pragma unroll
        for (int cc = 0; cc < 4; ++cc) kv[cc] = Ks[tx * 4 + cc][d];
#pragma unroll
        for (int rr = 0; rr < 4; ++rr)
#pragma unroll
            for (int cc = 0; cc < 4; ++cc) acc[rr][cc] += qv[rr] * kv[cc];
    }
#pragma unroll
    for (int rr = 0; rr < 4; ++rr)
#pragma unroll
        for (int cc = 0; cc < 4; ++cc) {
            int gi = i0 + ty * 4 + rr, gj = j0 + tx * 4 + cc;
            float cv = 1.0f - acc[rr][cc];
            C[((size_t)b * NN + gi) * NN + gj] = (_Float16)cv;
            CT[((size_t)b * NN + gj) * NN + gi] = (_Float16)cv;
        }
}

// ---------------- one Sinkhorn half-step ----------------
// out_i = eps*log_mu - eps * lse_j((in_j - M_ij)/eps), M row-major (8192 x 1024)
// ERR: also accumulate sum|out - out_old| into err[t]
template <bool ERR>
__global__ __launch_bounds__(256) void sink_kernel(const _Float16* __restrict__ M,
                                                   const float* __restrict__ vin,
                                                   float* __restrict__ uout,
                                                   float* __restrict__ err,
                                                   int t, float eln) {
    __shared__ float sv[NN];
    __shared__ float sdelta[4];
    __shared__ int sdone;
    int tid = threadIdx.x;
    int r0 = blockIdx.x * 4;      // 4 rows per block (one per wave)
    int b = r0 >> 10;
    // stage the dual vector for this batch in LDS
    ((float4*)sv)[tid] = ((const float4*)(vin + (size_t)b * NN))[tid];
    if (tid == 0) {
        int done = 0;
        for (int s = 0; s < t; ++s) done |= (err[s] < ERR_SUM_THRESH);
        sdone = done;
    }
    __syncthreads();
    if (sdone) return;

    int w = tid >> 6, lane = tid & 63;
    int r = r0 + w;
    const half8* crow = (const half8*)(M + (size_t)r * NN);
    half8 c0 = crow[2 * lane];
    half8 c1 = crow[2 * lane + 1];
    float4 v4[4];
#pragma unroll
    for (int kk = 0; kk < 4; ++kk) v4[kk] = ((const float4*)sv)[lane * 4 + kk];
    const float* vv = (const float*)v4;

    float y[16];
#pragma unroll
    for (int k = 0; k < 8; ++k) y[k] = (vv[k] - (float)c0[k]) * INV_EPS;
#pragma unroll
    for (int k = 0; k < 8; ++k) y[8 + k] = (vv[8 + k] - (float)c1[k]) * INV_EPS;

    float m = y[0];
#pragma unroll
    for (int k = 1; k < 16; ++k) m = fmaxf(m, y[k]);
    m = wave_max64(m);
    float s = 0.f;
#pragma unroll
    for (int k = 0; k < 16; ++k) s += __expf(y[k] - m);
    s = wave_sum64(s);
    float unew = eln - EPSF * (m + __logf(s));

    if (ERR) {
        if (lane == 0) {
            float d = fabsf(unew - uout[r]);
            uout[r] = unew;
            sdelta[w] = d;
        }
        __syncthreads();
        if (tid == 0) atomicAdd(&err[t], sdelta[0] + sdelta[1] + sdelta[2] + sdelta[3]);
    } else {
        if (lane == 0) uout[r] = unew;
    }
}

// ---------------- out = T@V + V, T = exp((-C + u_i + v_j)/eps) ----------------
__global__ __launch_bounds__(256) void final_kernel(const _Float16* __restrict__ C,
                                                    const float* __restrict__ u,
                                                    const float* __restrict__ v,
                                                    const float* __restrict__ V,
                                                    float* __restrict__ out) {
    int tid = threadIdx.x;
    int w = tid >> 6, lane = tid & 63;   // lane doubles as d index and j-chunk offset
    int r = blockIdx.x * 4 + w;
    int b = r >> 10;
    int i = r & (NN - 1);
    const _Float16* crow = C + (size_t)r * NN;
    const float* Vb = V + (size_t)b * NN * DD;
    const float* vb = v + (size_t)b * NN;
    float ui = u[r];
    float acc = 0.f;
    for (int j0 = 0; j0 < NN; j0 += 64) {
        float wl = __expf((ui + vb[j0 + lane] - (float)crow[j0 + lane]) * INV_EPS);
#pragma unroll 8
        for (int jj = 0; jj < 64; ++jj) {
            float wj = __shfl(wl, jj);
            acc += wj * Vb[(size_t)(j0 + jj) * DD + lane];
        }
    }
    out[(size_t)r * DD + lane] = acc + Vb[(size_t)i * DD + lane];
}

extern "C" void kernel_launch(void* const* d_in, const int* in_sizes, int n_in,
                              void* d_out, int out_size, void* d_ws, size_t ws_size,
                              hipStream_t stream) {
    const float* q = (const float*)d_in[0];
    const float* k = (const float*)d_in[1];
    const float* V = (const float*)d_in[2];
    float* out = (float*)d_out;

    char* ws = (char*)d_ws;
    const size_t C_BYTES = (size_t)BB * NN * NN * sizeof(_Float16);   // 16 MB
    _Float16* C  = (_Float16*)ws;
    _Float16* CT = (_Float16*)(ws + C_BYTES);
    float* Qn = (float*)(ws + 2 * C_BYTES);
    float* Kn = (float*)(ws + 2 * C_BYTES + (size_t)BB * NN * DD * 4);
    float* u  = (float*)(ws + 2 * C_BYTES + 2 * (size_t)BB * NN * DD * 4);
    float* v  = u + BB * NN;
    float* err = v + BB * NN;

    // zero u, v, err (ws is poisoned before every call)
    hipMemsetAsync(u, 0, (2 * BB * NN + MAX_ITER + 28) * sizeof(float), stream);

    norm_kernel<<<2048, 256, 0, stream>>>(q, Qn, BB * NN);
    norm_kernel<<<2048, 256, 0, stream>>>(k, Kn, BB * NN);
    cost_kernel<<<dim3(16, 16, 8), dim3(16, 16), 0, stream>>>(Qn, Kn, C, CT);

    float eln = EPSF * logf(1.0f / NN + 1e-8f);   // eps*log_mu == eps*log_nu
    for (int t = 0; t < MAX_ITER; ++t) {
        sink_kernel<true ><<<2048, 256, 0, stream>>>(C,  v, u, err, t, eln);
        sink_kernel<false><<<2048, 256, 0, stream>>>(CT, u, v, err, t, eln);
    }
    final_kernel<<<2048, 256, 0, stream>>>(C, u, v, V, out);
}